// Round 1
// baseline (795.199 us; speedup 1.0000x reference)
//
#include <hip/hip_runtime.h>
#include <math.h>

constexpr int NN = 4000;
constexpr int EE = 48000;
constexpr int CC = 64;
constexpr int ZZ = 10;
constexpr float RMAX = 5.0f;
constexpr float INV_AVG = 1.0f / 12.0f;

__device__ __forceinline__ float sigf(float x){ return 1.0f/(1.0f+expf(-x)); }
__device__ __forceinline__ float siluf(float x){ return x*sigf(x); }
__device__ __forceinline__ float dsiluf(float x){ float s=sigf(x); return s*(1.0f+x*(1.0f-s)); }

// ---------------- geometry + radial features + active-edge compaction ----------------
__global__ void k_geom(const float* __restrict__ pos, const float* __restrict__ shifts,
                       const int* __restrict__ ei, float* __restrict__ u3,
                       float* __restrict__ fr, float* __restrict__ dfr,
                       int* __restrict__ elist, int* __restrict__ ecount)
{
    int e = blockIdx.x*blockDim.x + threadIdx.x;
    if (e >= EE) return;
    int s = ei[e], r = ei[EE+e];
    float vx = pos[r*3+0]-pos[s*3+0]+shifts[e*3+0];
    float vy = pos[r*3+1]-pos[s*3+1]+shifts[e*3+1];
    float vz = pos[r*3+2]-pos[s*3+2]+shifts[e*3+2];
    float rr = sqrtf(vx*vx+vy*vy+vz*vz);
    float u = rr*(1.0f/RMAX);
    if (u >= 1.0f) return;              // env=0 -> f=0, df=0, w=0: no contribution at all
    int slot = atomicAdd(ecount, 1);
    elist[slot] = e;
    float inv = 1.0f/rr;
    u3[e*3+0]=vx*inv; u3[e*3+1]=vy*inv; u3[e*3+2]=vz*inv;
    float u2=u*u, u4=u2*u2, u5=u4*u;
    float env  = 1.0f - 21.0f*u5 + 35.0f*u5*u - 15.0f*u5*u2;
    float om   = 1.0f-u;
    float denv = -21.0f*u4*om*om;       // d env / d r
    const float A = 0.6324555320336759f; // sqrt(2/5)
#pragma unroll
    for (int n=1;n<=8;n++){
        float k = (float)n*(3.14159265358979323846f/RMAX);
        float sn = sinf(k*rr), cs = cosf(k*rr);
        float bess  = A*sn*inv;
        float dbess = A*(k*cs - sn*inv)*inv;
        fr [e*8+n-1] = bess*env;
        dfr[e*8+n-1] = dbess*env + bess*denv;
    }
}

// ---------------- species from one-hot ----------------
__global__ void k_spec(const float* __restrict__ x, int* __restrict__ spec)
{
    int n = blockIdx.x*blockDim.x + threadIdx.x;
    if (n >= NN) return;
    int sp = 0;
#pragma unroll
    for (int j=0;j<ZZ;j++) if (x[n*ZZ+j] > 0.5f) sp = j;
    spec[n] = sp;
}

__global__ void k_emb(const float* __restrict__ W_embed, const int* __restrict__ spec,
                      float* __restrict__ nf0)
{
    int idx = blockIdx.x*blockDim.x + threadIdx.x;
    if (idx >= NN*CC) return;
    int n = idx>>6, c = idx&63;
    nf0[idx] = W_embed[spec[n]*CC + c];
}

// ---------------- generic NxC @ CxC (optionally B^T, accumulate, bias) ----------------
template<bool TRB, bool ACC, bool BIAS>
__global__ void k_mat(const float* __restrict__ A, const float* __restrict__ B,
                      const float* __restrict__ bias, float* __restrict__ out, int nrows)
{
    __shared__ float Bs[64][65];
    __shared__ float rowA[4][64];
    int tid = threadIdx.x; int nl = tid>>6, c = tid&63;
    for (int i = tid; i < 64*64; i += 256) Bs[i>>6][i&63] = B[i];
    __syncthreads();
    int base = blockIdx.x*64;
    for (int it=0; it<16; ++it){
        int n = base + it*4 + nl;
        bool v = n < nrows;
        rowA[nl][c] = v ? A[n*64+c] : 0.0f;
        __syncthreads();
        float acc = 0.0f;
#pragma unroll
        for (int k=0;k<64;k++) acc += rowA[nl][k] * (TRB ? Bs[c][k] : Bs[k][c]);
        if (BIAS) acc += bias[c];
        if (v){
            if (ACC) out[n*64+c] += acc;
            else     out[n*64+c]  = acc;
        }
        __syncthreads();
    }
}

// ---------------- fused edge MLP + message + scatter (forward) ----------------
__global__ void k_edge_fwd(const float* __restrict__ fr, const int* __restrict__ elist,
                           const int* __restrict__ ecount, const int* __restrict__ ei,
                           const float* __restrict__ h,
                           const float* __restrict__ Wm1, const float* __restrict__ Wm2,
                           const float* __restrict__ Wm3, float* __restrict__ agg)
{
    __shared__ float W1[8][64];
    __shared__ float W2[64][65];
    __shared__ float W3[64][65];
    __shared__ float st1[4][64];
    __shared__ float st2[4][64];
    int tid = threadIdx.x, el = tid>>6, c = tid&63;
    int cnt = *ecount;
    int base = blockIdx.x*32;
    if (base >= cnt) return;
    for (int i=tid;i<512;i+=256)  W1[i>>6][i&63]=Wm1[i];
    for (int i=tid;i<4096;i+=256) W2[i>>6][i&63]=Wm2[i];
    for (int i=tid;i<4096;i+=256) W3[i>>6][i&63]=Wm3[(i>>6)*256 + ((i&63)<<2)]; // l=0 cols
    __syncthreads();
    for (int it=0; it<8; ++it){
        int slot = base + it*4 + el;
        bool valid = slot < cnt;
        int e = valid ? elist[slot] : 0;
        float f[8];
#pragma unroll
        for (int j=0;j<8;j++) f[j] = valid ? fr[e*8+j] : 0.0f;
        float t1=0.0f;
#pragma unroll
        for (int j=0;j<8;j++) t1 += f[j]*W1[j][c];
        st1[el][c] = siluf(t1);
        __syncthreads();
        float t2=0.0f;
#pragma unroll
        for (int k=0;k<64;k++) t2 += st1[el][k]*W2[k][c];
        st2[el][c] = siluf(t2);
        __syncthreads();
        float w0=0.0f;
#pragma unroll
        for (int k=0;k<64;k++) w0 += st2[el][k]*W3[k][c];
        if (valid){
            int s = ei[e], r = ei[EE+e];
            atomicAdd(&agg[r*64+c], w0 * h[s*64+c] * INV_AVG);
        }
        __syncthreads();
    }
}

// ---------------- fused node update + readout (forward) ----------------
template<int LAYER>
__global__ void k_node_fwd(const float* __restrict__ agg, const float* __restrict__ nf0,
    const float* __restrict__ O, const float* __restrict__ P, const float* __restrict__ S,
    const float* __restrict__ poly, const float* __restrict__ asc, const int* __restrict__ spec,
    const float* __restrict__ Wr1, const float* __restrict__ wr,
    float* __restrict__ sbuf, float* __restrict__ nfout, float* __restrict__ zbuf,
    float* __restrict__ node_e)
{
    __shared__ float Os[64][65], Ps[64][65], Ss[64][65];
    __shared__ float rowA[4][64], rowB[4][64];
    __shared__ float Wr1s[64][17];
    int tid=threadIdx.x, nl=tid>>6, c=tid&63;
    for (int i=tid;i<4096;i+=256){ Os[i>>6][i&63]=O[i]; Ps[i>>6][i&63]=P[i]; Ss[i>>6][i&63]=S[i]; }
    if (LAYER==1) for (int i=tid;i<1024;i+=256) Wr1s[i>>4][i&15] = Wr1[i];
    float p0=poly[c], p1=poly[64+c], p2=poly[128+c];
    __syncthreads();
    int base = blockIdx.x*16;
    for (int it=0; it<4; ++it){
        int n = base + it*4 + nl;
        bool v = n < NN;
        rowA[nl][c] = v ? agg[n*64+c] : 0.0f;
        rowB[nl][c] = v ? nf0[n*64+c] : 0.0f;
        __syncthreads();
        float s=0.0f, scp=0.0f;
#pragma unroll
        for (int k=0;k<64;k++){ s += rowA[nl][k]*Os[k][c]; scp += rowB[nl][k]*Ss[k][c]; }
        float gate = p0 + p1*s + p2*s*s;
        float vv = s*gate;
        __syncthreads();
        rowA[nl][c] = vv;
        __syncthreads();
        float nf=0.0f;
#pragma unroll
        for (int k=0;k<64;k++) nf += rowA[nl][k]*Ps[k][c];
        float a = v ? asc[spec[n]*CC + c] : 0.0f;
        nf += scp*a;
        if (v){ sbuf[n*64+c]=s; nfout[n*64+c]=nf; }
        if (LAYER==0){
            float contrib = nf * wr[c];
#pragma unroll
            for (int off=32; off; off>>=1) contrib += __shfl_xor(contrib, off);
            if (v && c==0) node_e[n] = contrib;
        } else {
            __syncthreads();
            rowA[nl][c] = nf;
            __syncthreads();
            float val = 0.0f;
            if (c < 16){
                float zz = 0.0f;
#pragma unroll
                for (int k=0;k<64;k++) zz += rowA[nl][k]*Wr1s[k][c];
                if (v) zbuf[n*16+c] = zz;
                val = siluf(zz)*wr[c];
            }
#pragma unroll
            for (int off=8; off; off>>=1) val += __shfl_xor(val, off);
            if (v && c==0) node_e[n] += val;
        }
        __syncthreads();
    }
}

// ---------------- backward: readout-2 -> g_nf1 ----------------
__global__ void k_bz(const float* __restrict__ z, const float* __restrict__ Wr1,
                     const float* __restrict__ wr2, float* __restrict__ gnf)
{
    int idx = blockIdx.x*blockDim.x + threadIdx.x;
    if (idx >= NN*CC) return;
    int n = idx>>6, c = idx&63;
    float acc=0.0f;
#pragma unroll
    for (int k=0;k<16;k++){
        float zz = z[n*16+k];
        acc += wr2[k]*dsiluf(zz)*Wr1[c*16+k];
    }
    gnf[idx]=acc;
}

// ---------------- backward node: g_in -> g_agg (and sc-path grad) ----------------
template<bool HAS_SC>
__global__ void k_bnode(const float* __restrict__ gin, const float* __restrict__ sbuf,
    const float* __restrict__ O, const float* __restrict__ P, const float* __restrict__ S,
    const float* __restrict__ poly, const float* __restrict__ asc, const int* __restrict__ spec,
    float* __restrict__ gagg, float* __restrict__ gout)
{
    __shared__ float Os[64][65], Ps[64][65], Ss[64][65];
    __shared__ float rowA[4][64], rowB[4][64];
    int tid=threadIdx.x, nl=tid>>6, c=tid&63;
    for (int i=tid;i<4096;i+=256){ Os[i>>6][i&63]=O[i]; Ps[i>>6][i&63]=P[i]; }
    if constexpr (HAS_SC) { for (int i=tid;i<4096;i+=256) Ss[i>>6][i&63]=S[i]; }
    float p0=poly[c], p1=poly[64+c], p2=poly[128+c];
    __syncthreads();
    int base = blockIdx.x*16;
    for (int it=0; it<4; ++it){
        int n = base + it*4 + nl;
        bool v = n < NN;
        float g = v ? gin[n*64+c] : 0.0f;
        rowA[nl][c] = g;
        if constexpr (HAS_SC) rowB[nl][c] = g * (v ? asc[spec[n]*CC+c] : 0.0f);
        __syncthreads();
        float gv=0.0f, gsc=0.0f;
#pragma unroll
        for (int d=0;d<64;d++){
            gv += rowA[nl][d]*Ps[c][d];
            if constexpr (HAS_SC) gsc += rowB[nl][d]*Ss[c][d];
        }
        float s = v ? sbuf[n*64+c] : 0.0f;
        float gate = p0 + p1*s + p2*s*s;
        float dvds = gate + s*(p1 + 2.0f*p2*s);
        float gs = gv*dvds;
        __syncthreads();
        rowA[nl][c] = gs;
        __syncthreads();
        float ga=0.0f;
#pragma unroll
        for (int d=0;d<64;d++) ga += rowA[nl][d]*Os[c][d];
        if (v){ gagg[n*64+c]=ga; if constexpr (HAS_SC) gout[n*64+c]=gsc; }
        __syncthreads();
    }
}

// ---------------- backward edge: recompute MLP, backprop to radial -> forces ----------------
template<bool ACCGH>
__global__ void k_edge_bwd(const float* __restrict__ fr, const float* __restrict__ dfr,
                           const float* __restrict__ u3, const int* __restrict__ elist,
                           const int* __restrict__ ecount, const int* __restrict__ ei,
                           const float* __restrict__ h, const float* __restrict__ gagg,
                           const float* __restrict__ Wm1, const float* __restrict__ Wm2,
                           const float* __restrict__ Wm3,
                           float* __restrict__ gh, float* __restrict__ gpos)
{
    __shared__ float W1[8][64];
    __shared__ float W2[64][65];
    __shared__ float W3[64][65];
    __shared__ float st1[4][64];
    __shared__ float st2[4][64];
    __shared__ float stg[4][64];
    int tid=threadIdx.x, el=tid>>6, c=tid&63;
    int cnt = *ecount;
    int base = blockIdx.x*32;
    if (base >= cnt) return;
    for (int i=tid;i<512;i+=256)  W1[i>>6][i&63]=Wm1[i];
    for (int i=tid;i<4096;i+=256) W2[i>>6][i&63]=Wm2[i];
    for (int i=tid;i<4096;i+=256) W3[i>>6][i&63]=Wm3[(i>>6)*256 + ((i&63)<<2)];
    __syncthreads();
    for (int it=0; it<8; ++it){
        int slot = base + it*4 + el;
        bool valid = slot < cnt;
        int e = valid ? elist[slot] : 0;
        float f[8];
#pragma unroll
        for (int j=0;j<8;j++) f[j] = valid ? fr[e*8+j] : 0.0f;
        float t1=0.0f;
#pragma unroll
        for (int j=0;j<8;j++) t1 += f[j]*W1[j][c];
        st1[el][c] = siluf(t1);
        __syncthreads();
        float t2=0.0f;
#pragma unroll
        for (int k=0;k<64;k++) t2 += st1[el][k]*W2[k][c];
        st2[el][c] = siluf(t2);
        __syncthreads();
        float w0=0.0f;
#pragma unroll
        for (int k=0;k<64;k++) w0 += st2[el][k]*W3[k][c];
        int s=0, r=0; float hs=0.0f, gm=0.0f;
        if (valid){ s=ei[e]; r=ei[EE+e]; hs=h[s*64+c]; gm=gagg[r*64+c]*INV_AVG; }
        if (ACCGH && valid) atomicAdd(&gh[s*64+c], gm*w0);
        stg[el][c] = gm*hs;                 // g_w0
        __syncthreads();
        float ga2=0.0f;
#pragma unroll
        for (int k=0;k<64;k++) ga2 += stg[el][k]*W3[c][k];   // lane c == hidden index
        float gt2 = ga2*dsiluf(t2);
        __syncthreads();
        st1[el][c] = gt2;                   // reuse (a1 no longer needed)
        __syncthreads();
        float ga1=0.0f;
#pragma unroll
        for (int k=0;k<64;k++) ga1 += st1[el][k]*W2[k][c];
        float gt1 = ga1*dsiluf(t1);
        float wd=0.0f;
        if (valid){
#pragma unroll
            for (int j=0;j<8;j++) wd += W1[j][c]*dfr[e*8+j];
        }
        float p = gt1*wd;                   // partial of dE/dr
#pragma unroll
        for (int off=32; off; off>>=1) p += __shfl_xor(p, off);
        if (valid){
            if (c < 3)                 atomicAdd(&gpos[r*3+c],  u3[e*3+c]*p);
            else if (c >= 32 && c < 35){ int d=c-32; atomicAdd(&gpos[s*3+d], -u3[e*3+d]*p); }
        }
        __syncthreads();
    }
}

// ---------------- final: snap reduce, node_e copy, forces = -gpos ----------------
__global__ void k_final(const float* __restrict__ node_e, const int* __restrict__ batch,
                        const float* __restrict__ gpos, float* __restrict__ out)
{
    __shared__ float part[8];
    int tid=threadIdx.x;
    if (tid<8) part[tid]=0.0f;
    __syncthreads();
    int n = blockIdx.x*blockDim.x + tid;
    if (n<NN){
        float ne = node_e[n];
        out[8+n] = ne;
        atomicAdd(&part[batch[n]], ne);
        out[8+NN + n*3+0] = -gpos[n*3+0];
        out[8+NN + n*3+1] = -gpos[n*3+1];
        out[8+NN + n*3+2] = -gpos[n*3+2];
    }
    __syncthreads();
    if (tid<8) atomicAdd(&out[tid], part[tid]);
}

extern "C" void kernel_launch(void* const* d_in, const int* in_sizes, int n_in,
                              void* d_out, int out_size, void* d_ws, size_t ws_size,
                              hipStream_t stream)
{
    (void)in_sizes; (void)n_in; (void)out_size; (void)ws_size;
    const float* pos    = (const float*)d_in[0];
    const float* x      = (const float*)d_in[1];
    const float* shifts = (const float*)d_in[2];
    const float* W_embed= (const float*)d_in[3];
    const float* W_up   = (const float*)d_in[4];
    const float* Wm1    = (const float*)d_in[5];
    const float* Wm2    = (const float*)d_in[6];
    const float* Wm3    = (const float*)d_in[7];
    const float* W_out  = (const float*)d_in[8];
    const float* W_sc   = (const float*)d_in[9];
    const float* a_sc   = (const float*)d_in[10];
    const float* w_poly = (const float*)d_in[11];
    const float* W_prod = (const float*)d_in[12];
    const float* w_r0   = (const float*)d_in[13];
    const float* W_r1   = (const float*)d_in[14];
    const float* w_r2   = (const float*)d_in[15];
    const int*   ei     = (const int*)d_in[16];
    const int*   batch  = (const int*)d_in[17];
    float* out = (float*)d_out;

    float* F = (float*)d_ws;
    float* u3   = F; F += 3*EE;
    float* fr   = F; F += 8*EE;
    float* dfr  = F; F += 8*EE;
    float* nf0  = F; F += NN*CC;
    float* nf1  = F; F += NN*CC;
    float* nf2  = F; F += NN*CC;
    float* h0   = F; F += NN*CC;
    float* h1   = F; F += NN*CC;
    float* s0   = F; F += NN*CC;
    float* s1   = F; F += NN*CC;
    float* agg  = F; F += NN*CC;
    float* zb   = F; F += NN*16;
    float* nodee= F; F += NN;
    float* gnf1 = F; F += NN*CC;
    float* gagg = F; F += NN*CC;
    float* gacc = F; F += NN*CC;
    float* ghb  = F; F += NN*CC;
    float* gpos = F; F += NN*3;
    int* spec   = (int*)F; F += NN;
    int* elist  = (int*)F; F += EE;
    int* ecount = (int*)F; F += 1;

    const float* U0 = W_up;             const float* U1 = W_up   + 4*CC*CC;
    const float* O0 = W_out;            const float* O1 = W_out  + 4*CC*CC;
    const float* S0 = W_sc;             const float* S1 = W_sc   + 4*CC*CC;
    const float* P0 = W_prod;           const float* P1 = W_prod + 4*CC*CC;
    const float* M1_0=Wm1,  *M1_1=Wm1+8*64;
    const float* M2_0=Wm2,  *M2_1=Wm2+64*64;
    const float* M3_0=Wm3,  *M3_1=Wm3+64*256;
    const float* asc0=a_sc, *asc1=a_sc+ZZ*CC;
    const float* pl0=w_poly,*pl1=w_poly+3*CC;

    hipMemsetAsync(ecount, 0, sizeof(int), stream);
    k_geom<<<(EE+255)/256, 256, 0, stream>>>(pos, shifts, ei, u3, fr, dfr, elist, ecount);
    k_spec<<<(NN+255)/256, 256, 0, stream>>>(x, spec);
    k_emb<<<(NN*CC+255)/256, 256, 0, stream>>>(W_embed, spec, nf0);

    // ---- layer 0 forward ----
    k_mat<false,false,false><<<63,256,0,stream>>>(nf0, U0, nullptr, h0, NN);
    hipMemsetAsync(agg, 0, NN*CC*sizeof(float), stream);
    k_edge_fwd<<<1500,256,0,stream>>>(fr, elist, ecount, ei, h0, M1_0, M2_0, M3_0, agg);
    k_node_fwd<0><<<250,256,0,stream>>>(agg, nf0, O0,P0,S0, pl0, asc0, spec, nullptr, w_r0,
                                        s0, nf1, nullptr, nodee);
    // ---- layer 1 forward ----
    k_mat<false,false,false><<<63,256,0,stream>>>(nf1, U1, nullptr, h1, NN);
    hipMemsetAsync(agg, 0, NN*CC*sizeof(float), stream);
    k_edge_fwd<<<1500,256,0,stream>>>(fr, elist, ecount, ei, h1, M1_1, M2_1, M3_1, agg);
    k_node_fwd<1><<<250,256,0,stream>>>(agg, nf1, O1,P1,S1, pl1, asc1, spec, W_r1, w_r2,
                                        s1, nf2, zb, nodee);

    // ---- backward ----
    k_bz<<<(NN*CC+255)/256,256,0,stream>>>(zb, W_r1, w_r2, gnf1);
    k_bnode<true><<<250,256,0,stream>>>(gnf1, s1, O1,P1,S1, pl1, asc1, spec, gagg, gacc);
    hipMemsetAsync(ghb, 0, NN*CC*sizeof(float), stream);
    hipMemsetAsync(gpos, 0, NN*3*sizeof(float), stream);
    k_edge_bwd<true><<<1500,256,0,stream>>>(fr, dfr, u3, elist, ecount, ei, h1, gagg,
                                            M1_1, M2_1, M3_1, ghb, gpos);
    // gacc += ghb @ U1^T + w_r0   (h-path into nf0_new, plus layer-0 readout grad)
    k_mat<true,true,true><<<63,256,0,stream>>>(ghb, U1, w_r0, gacc, NN);
    k_bnode<false><<<250,256,0,stream>>>(gacc, s0, O0,P0,nullptr, pl0, nullptr, nullptr,
                                         gagg, nullptr);
    k_edge_bwd<false><<<1500,256,0,stream>>>(fr, dfr, u3, elist, ecount, ei, h0, gagg,
                                             M1_0, M2_0, M3_0, nullptr, gpos);

    hipMemsetAsync(out, 0, 8*sizeof(float), stream);
    k_final<<<(NN+255)/256,256,0,stream>>>(nodee, batch, gpos, out);
}

// Round 2
// 375.720 us; speedup vs baseline: 2.1165x; 2.1165x over previous
//
#include <hip/hip_runtime.h>
#include <math.h>

constexpr int NN = 4000;
constexpr int EE = 48000;
constexpr int ZZ = 10;
constexpr float RMAX = 5.0f;
constexpr float INV_AVG = 1.0f / 12.0f;

__device__ __forceinline__ float rl(float v, int lane){
    return __uint_as_float(__builtin_amdgcn_readlane(__float_as_uint(v), lane));
}
__device__ __forceinline__ float sigf(float x){ return 1.0f/(1.0f+__expf(-x)); }
__device__ __forceinline__ float siluf(float x){ return x*sigf(x); }
__device__ __forceinline__ float dsiluf(float x){ float s=sigf(x); return s*(1.0f+x*(1.0f-s)); }

// broadcast matvec: out_lane = sum_k readlane(src,k) * W[k]   (no LDS, no barriers)
__device__ __forceinline__ float bmv64(float src, const float (&W)[64]){
    float a0=0.f,a1=0.f,a2=0.f,a3=0.f;
#pragma unroll
    for (int k=0;k<64;k+=4){
        a0 += rl(src,k+0)*W[k+0];
        a1 += rl(src,k+1)*W[k+1];
        a2 += rl(src,k+2)*W[k+2];
        a3 += rl(src,k+3)*W[k+3];
    }
    return (a0+a1)+(a2+a3);
}
// per-lane contiguous row load (p already includes lane*64)
__device__ __forceinline__ void load_row64(const float* __restrict__ p, float (&W)[64]){
#pragma unroll
    for (int i=0;i<16;i++){
        float4 v = reinterpret_cast<const float4*>(p)[i];
        W[4*i]=v.x; W[4*i+1]=v.y; W[4*i+2]=v.z; W[4*i+3]=v.w;
    }
}
// column load: W[k] = p[k*64+lane] (coalesced across lanes)
__device__ __forceinline__ void load_col64(const float* __restrict__ p, int lane, float (&W)[64]){
#pragma unroll
    for (int k=0;k<64;k++) W[k] = p[k*64+lane];
}

// ---------------- geometry + radial features + active-edge compaction ----------------
__global__ void k_geom(const float* __restrict__ pos, const float* __restrict__ shifts,
                       const int* __restrict__ ei, float* __restrict__ u3,
                       float* __restrict__ fr, float* __restrict__ dfr,
                       int* __restrict__ elist, int* __restrict__ ecount)
{
    int e = blockIdx.x*256 + threadIdx.x;
    if (e >= EE) return;
    int s = ei[e], r = ei[EE+e];
    float vx = pos[r*3+0]-pos[s*3+0]+shifts[e*3+0];
    float vy = pos[r*3+1]-pos[s*3+1]+shifts[e*3+1];
    float vz = pos[r*3+2]-pos[s*3+2]+shifts[e*3+2];
    float rr = sqrtf(vx*vx+vy*vy+vz*vz);
    float u = rr*(1.0f/RMAX);
    if (u >= 1.0f) return;     // env=0 -> zero message and zero force
    int slot = atomicAdd(ecount, 1);
    elist[slot] = e;
    float inv = 1.0f/rr;
    u3[e*3+0]=vx*inv; u3[e*3+1]=vy*inv; u3[e*3+2]=vz*inv;
    float u2=u*u, u4=u2*u2, u5=u4*u;
    float env  = 1.0f - 21.0f*u5 + 35.0f*u5*u - 15.0f*u5*u2;
    float om   = 1.0f-u;
    float denv = -21.0f*u4*om*om;
    const float A = 0.6324555320336759f;   // sqrt(2/RMAX)
    const float K1 = 3.14159265358979f/RMAX;
    float a  = K1*rr;
    float s1 = __sinf(a), c1 = __cosf(a);
    float sp = 0.0f, cp = 1.0f, sn = s1, cn = c1;
#pragma unroll
    for (int n=1;n<=8;n++){
        float k = (float)n*K1;
        float bess  = A*sn*inv;
        float dbess = A*(k*cn - sn*inv)*inv;
        fr [e*8+n-1] = bess*env;
        dfr[e*8+n-1] = dbess*env + bess*denv;
        float s2 = 2.0f*c1*sn - sp; sp=sn; sn=s2;
        float c2 = 2.0f*c1*cn - cp; cp=cn; cn=c2;
    }
}

__global__ void k_spec(const float* __restrict__ x, int* __restrict__ spec)
{
    int n = blockIdx.x*256 + threadIdx.x;
    if (n >= NN) return;
    int sp = 0;
#pragma unroll
    for (int j=0;j<ZZ;j++) if (x[n*ZZ+j] > 0.5f) sp = j;
    spec[n] = sp;
}

// per-species tables T0 = WE@U0, SC0 = (WE@S0)*asc0 ; gather Wm3 l=0 slice -> dense
__global__ void k_pre(const float* __restrict__ WE, const float* __restrict__ W_up,
                      const float* __restrict__ W_sc, const float* __restrict__ a_sc,
                      const float* __restrict__ Wm3,
                      float* __restrict__ T0, float* __restrict__ SC0, float* __restrict__ W3z)
{
    int b = blockIdx.x;
    if (b < 32){
        int idx = b*256 + threadIdx.x;       // 0..8191 : 2 layers x 4096
        int l = idx >> 12;
        int kc = idx & 4095;
        int k = kc >> 6, c = kc & 63;
        W3z[idx] = Wm3[l*64*256 + k*256 + 4*c];
    } else {
        int wv = (b-32)*4 + (threadIdx.x>>6);
        int lane = threadIdx.x & 63;
        if (wv < ZZ){
            float wev = WE[wv*64 + lane];
            float t=0.f, sc=0.f;
#pragma unroll
            for (int c=0;c<64;c++){
                float w = rl(wev,c);
                t  += w*W_up[c*64+lane];
                sc += w*W_sc[c*64+lane];
            }
            T0[wv*64+lane]  = t;
            SC0[wv*64+lane] = sc * a_sc[wv*64+lane];
        }
    }
}

// ---------------- fused edge MLP forward (wave-per-edge, weights in VGPRs) ----------------
template<int L>
__global__ void k_edge_fwd(const float* __restrict__ fr, const int* __restrict__ elist,
                           const int* __restrict__ ecount, const int* __restrict__ ei,
                           const int* __restrict__ spec, const float* __restrict__ T0,
                           const float* __restrict__ h1,
                           const float* __restrict__ W1, const float* __restrict__ W2,
                           const float* __restrict__ W3z,
                           float* __restrict__ agg, float* __restrict__ t2b,
                           float* __restrict__ w0b)
{
    int lane = threadIdx.x & 63;
    int wid  = (blockIdx.x*blockDim.x + threadIdx.x) >> 6;
    int nw   = (gridDim.x*blockDim.x) >> 6;
    int cnt  = ecount[0];
    float W1c[8], W2c[64], W3c[64];
#pragma unroll
    for (int j=0;j<8;j++) W1c[j] = W1[j*64+lane];
    load_col64(W2,  lane, W2c);
    load_col64(W3z, lane, W3c);
    for (int slot=wid; slot<cnt; slot+=nw){
        int e = elist[slot];
        int s = ei[e], r = ei[EE+e];
        float fv = fr[e*8 + (lane&7)];
        float t1=0.f;
#pragma unroll
        for (int j=0;j<8;j++) t1 += rl(fv,j)*W1c[j];
        float a1v = siluf(t1);
        float t2  = bmv64(a1v, W2c);
        t2b[slot*64+lane] = t2;
        float a2v = siluf(t2);
        float w0  = bmv64(a2v, W3c);
        if (L==1) w0b[slot*64+lane] = w0;
        float h = (L==0) ? T0[spec[s]*64+lane] : h1[s*64+lane];
        atomicAdd(&agg[r*64+lane], w0*h*INV_AVG);
    }
}

// ---------------- node update fwd, layer0 (+fused h1 = nf1@U1 and readout0) ----------------
__global__ void k_node_fwd0(const float* __restrict__ agg, const float* __restrict__ SC0,
                            const int* __restrict__ spec, const float* __restrict__ Wout,
                            const float* __restrict__ Wprod, const float* __restrict__ Wup1,
                            const float* __restrict__ poly, const float* __restrict__ wr0,
                            float* __restrict__ s0, float* __restrict__ nf1,
                            float* __restrict__ h1, float* __restrict__ nodee)
{
    int lane = threadIdx.x & 63;
    int wid  = (blockIdx.x*blockDim.x + threadIdx.x) >> 6;
    int nw   = (gridDim.x*blockDim.x) >> 6;
    float Oc[64], Pc[64], Uc[64];
    load_col64(Wout, lane, Oc);
    load_col64(Wprod,lane, Pc);
    load_col64(Wup1, lane, Uc);
    float p0=poly[lane], p1=poly[64+lane], p2=poly[128+lane];
    float w0r = wr0[lane];
    for (int n=wid; n<NN; n+=nw){
        float av = agg[n*64+lane];
        float s  = bmv64(av, Oc);
        float gate = p0 + p1*s + p2*s*s;
        float v  = s*gate;
        float nf = bmv64(v, Pc) + SC0[spec[n]*64+lane];
        s0 [n*64+lane] = s;
        nf1[n*64+lane] = nf;
        h1 [n*64+lane] = bmv64(nf, Uc);
        float ne = nf*w0r;
#pragma unroll
        for (int off=32;off;off>>=1) ne += __shfl_xor(ne,off);
        if (lane==0) nodee[n] = ne;
    }
}

// ---------------- node update fwd, layer1 ----------------
__global__ void k_node_fwd1(const float* __restrict__ agg, const float* __restrict__ nf1,
                            const int* __restrict__ spec, const float* __restrict__ Wout,
                            const float* __restrict__ Wprod, const float* __restrict__ Wsc,
                            const float* __restrict__ asc, const float* __restrict__ poly,
                            float* __restrict__ s1, float* __restrict__ nf2)
{
    int lane = threadIdx.x & 63;
    int wid  = (blockIdx.x*blockDim.x + threadIdx.x) >> 6;
    int nw   = (gridDim.x*blockDim.x) >> 6;
    float Oc[64], Pc[64], Sc[64];
    load_col64(Wout, lane, Oc);
    load_col64(Wprod,lane, Pc);
    load_col64(Wsc,  lane, Sc);
    float p0=poly[lane], p1=poly[64+lane], p2=poly[128+lane];
    for (int n=wid; n<NN; n+=nw){
        float av  = agg[n*64+lane];
        float nfv = nf1[n*64+lane];
        float s   = bmv64(av, Oc);
        float gate = p0 + p1*s + p2*s*s;
        float v   = s*gate;
        float scp = bmv64(nfv, Sc);
        float nf  = bmv64(v, Pc) + scp*asc[spec[n]*64+lane];
        s1 [n*64+lane] = s;
        nf2[n*64+lane] = nf;
    }
}

// ---------------- readout layer1: node_e final + gnf2 ----------------
__global__ void k_read1(const float* __restrict__ nf2, const float* __restrict__ Wr1,
                        const float* __restrict__ wr2, float* __restrict__ nodee,
                        float* __restrict__ gnf2)
{
    int lane = threadIdx.x & 63;
    int wid  = (blockIdx.x*blockDim.x + threadIdx.x) >> 6;
    int nw   = (gridDim.x*blockDim.x) >> 6;
    int j = lane & 15;
    float Wcol[64];
#pragma unroll
    for (int c=0;c<64;c++) Wcol[c] = Wr1[c*16 + j];
    float Wrow[16];
#pragma unroll
    for (int i=0;i<4;i++){
        float4 v = reinterpret_cast<const float4*>(Wr1 + lane*16)[i];
        Wrow[4*i]=v.x; Wrow[4*i+1]=v.y; Wrow[4*i+2]=v.z; Wrow[4*i+3]=v.w;
    }
    float w2 = wr2[j];
    for (int n=wid; n<NN; n+=nw){
        float nv = nf2[n*64+lane];
        float z  = bmv64(nv, Wcol);        // z_{lane&15}, replicated 4x
        float ne = siluf(z)*w2;
#pragma unroll
        for (int off=32;off;off>>=1) ne += __shfl_xor(ne,off);
        ne *= 0.25f;                        // each j counted 4 times
        float gz = w2*dsiluf(z);
        float g = 0.f;
#pragma unroll
        for (int jj=0;jj<16;jj++) g += rl(gz,jj)*Wrow[jj];
        gnf2[n*64+lane] = g;
        if (lane==0) nodee[n] += ne;
    }
}

// ---------------- backward node block: gin -> gagg (+sc-path grad) ----------------
template<bool SC>
__global__ void k_bnode(const float* __restrict__ gin, const float* __restrict__ sbuf,
                        const float* __restrict__ Wout, const float* __restrict__ Wprod,
                        const float* __restrict__ Wsc, const float* __restrict__ asc,
                        const int* __restrict__ spec, const float* __restrict__ poly,
                        float* __restrict__ gagg, float* __restrict__ gsc)
{
    int lane = threadIdx.x & 63;
    int wid  = (blockIdx.x*blockDim.x + threadIdx.x) >> 6;
    int nw   = (gridDim.x*blockDim.x) >> 6;
    float Pr[64], Or[64], Sr[64];
    load_row64(Wprod + lane*64, Pr);
    load_row64(Wout  + lane*64, Or);
    if (SC) load_row64(Wsc + lane*64, Sr);
    float p0=poly[lane], p1=poly[64+lane], p2=poly[128+lane];
    for (int n=wid; n<NN; n+=nw){
        float g  = gin[n*64+lane];
        float gv = bmv64(g, Pr);
        float s  = sbuf[n*64+lane];
        float gate = p0 + p1*s + p2*s*s;
        float gs = gv*(gate + s*(p1 + 2.0f*p2*s));
        gagg[n*64+lane] = bmv64(gs, Or);
        if (SC){
            float ga = g * asc[spec[n]*64+lane];
            gsc[n*64+lane] = bmv64(ga, Sr);
        }
    }
}

// ---------------- assemble gnf1 = ghb@U1^T + gacc + wr0 ----------------
__global__ void k_mmT(const float* __restrict__ ghb, const float* __restrict__ gacc,
                      const float* __restrict__ Wup1, const float* __restrict__ wr0,
                      float* __restrict__ gnf1)
{
    int lane = threadIdx.x & 63;
    int wid  = (blockIdx.x*blockDim.x + threadIdx.x) >> 6;
    int nw   = (gridDim.x*blockDim.x) >> 6;
    float Ur[64];
    load_row64(Wup1 + lane*64, Ur);
    float w0r = wr0[lane];
    for (int n=wid; n<NN; n+=nw){
        float gv = ghb[n*64+lane];
        gnf1[n*64+lane] = bmv64(gv, Ur) + gacc[n*64+lane] + w0r;
    }
}

// ---------------- backward edge MLP -> gpos (+gh for layer1) ----------------
template<int L>
__global__ void k_edge_bwd(const float* __restrict__ fr, const float* __restrict__ dfr,
                           const float* __restrict__ u3, const int* __restrict__ elist,
                           const int* __restrict__ ecount, const int* __restrict__ ei,
                           const int* __restrict__ spec, const float* __restrict__ T0,
                           const float* __restrict__ h1, const float* __restrict__ gagg,
                           const float* __restrict__ t2b, const float* __restrict__ w0b,
                           const float* __restrict__ W1, const float* __restrict__ W2,
                           const float* __restrict__ W3z,
                           float* __restrict__ ghb, float* __restrict__ gpos)
{
    int lane = threadIdx.x & 63;
    int wid  = (blockIdx.x*blockDim.x + threadIdx.x) >> 6;
    int nw   = (gridDim.x*blockDim.x) >> 6;
    int cnt  = ecount[0];
    float W3r[64], W2r[64], W1c[8];
    load_row64(W3z + lane*64, W3r);
    load_row64(W2  + lane*64, W2r);
#pragma unroll
    for (int j=0;j<8;j++) W1c[j] = W1[j*64+lane];
    for (int slot=wid; slot<cnt; slot+=nw){
        int e = elist[slot];
        int s = ei[e], r = ei[EE+e];
        float gm = gagg[r*64+lane]*INV_AVG;
        float h  = (L==0) ? T0[spec[s]*64+lane] : h1[s*64+lane];
        float gw0 = gm*h;
        if (L==1) atomicAdd(&ghb[s*64+lane], gm*w0b[slot*64+lane]);
        float ga2 = bmv64(gw0, W3r);
        float t2v = t2b[slot*64+lane];
        float gt2 = ga2*dsiluf(t2v);
        float ga1 = bmv64(gt2, W2r);
        float fv  = fr [e*8+(lane&7)];
        float dfv = dfr[e*8+(lane&7)];
        float t1=0.f, wd=0.f;
#pragma unroll
        for (int j=0;j<8;j++){ t1 += rl(fv,j)*W1c[j]; wd += rl(dfv,j)*W1c[j]; }
        float gt1 = ga1*dsiluf(t1);
        float p = gt1*wd;
#pragma unroll
        for (int off=32;off;off>>=1) p += __shfl_xor(p,off);
        if (lane<3) atomicAdd(&gpos[r*3+lane],  u3[e*3+lane]*p);
        else if (lane>=32 && lane<35){ int d=lane-32; atomicAdd(&gpos[s*3+d], -u3[e*3+d]*p); }
    }
}

// ---------------- final: snap reduce, node_e copy, forces ----------------
__global__ void k_final(const float* __restrict__ node_e, const int* __restrict__ batch,
                        const float* __restrict__ gpos, float* __restrict__ out)
{
    __shared__ float part[8];
    int tid=threadIdx.x;
    if (tid<8) part[tid]=0.0f;
    __syncthreads();
    int n = blockIdx.x*256 + tid;
    if (n<NN){
        float ne = node_e[n];
        out[8+n] = ne;
        atomicAdd(&part[batch[n]], ne);
        out[8+NN + n*3+0] = -gpos[n*3+0];
        out[8+NN + n*3+1] = -gpos[n*3+1];
        out[8+NN + n*3+2] = -gpos[n*3+2];
    }
    __syncthreads();
    if (tid<8) atomicAdd(&out[tid], part[tid]);
}

extern "C" void kernel_launch(void* const* d_in, const int* in_sizes, int n_in,
                              void* d_out, int out_size, void* d_ws, size_t ws_size,
                              hipStream_t stream)
{
    (void)in_sizes; (void)n_in; (void)out_size; (void)ws_size;
    const float* pos    = (const float*)d_in[0];
    const float* x      = (const float*)d_in[1];
    const float* shifts = (const float*)d_in[2];
    const float* W_embed= (const float*)d_in[3];
    const float* W_up   = (const float*)d_in[4];
    const float* Wm1    = (const float*)d_in[5];
    const float* Wm2    = (const float*)d_in[6];
    const float* Wm3    = (const float*)d_in[7];
    const float* W_out  = (const float*)d_in[8];
    const float* W_sc   = (const float*)d_in[9];
    const float* a_sc   = (const float*)d_in[10];
    const float* w_poly = (const float*)d_in[11];
    const float* W_prod = (const float*)d_in[12];
    const float* w_r0   = (const float*)d_in[13];
    const float* W_r1   = (const float*)d_in[14];
    const float* w_r2   = (const float*)d_in[15];
    const int*   ei     = (const int*)d_in[16];
    const int*   batch  = (const int*)d_in[17];
    float* out = (float*)d_out;

    float* F = (float*)d_ws;
    float* u3   = F; F += 3*EE;
    float* fr   = F; F += 8*EE;
    float* dfr  = F; F += 8*EE;
    float* t2b0 = F; F += (size_t)EE*64;
    float* t2b1 = F; F += (size_t)EE*64;
    float* w0b1 = F; F += (size_t)EE*64;
    float* h1   = F; F += NN*64;
    float* nf1  = F; F += NN*64;
    float* nf2  = F; F += NN*64;
    float* s0   = F; F += NN*64;
    float* s1   = F; F += NN*64;
    float* agg0 = F; F += NN*64;
    float* agg1 = F; F += NN*64;
    float* nodee= F; F += NN;
    float* gnf2 = F; F += NN*64;
    float* gagg1= F; F += NN*64;
    float* gagg0= F; F += NN*64;
    float* gacc = F; F += NN*64;
    float* ghb  = F; F += NN*64;
    float* gnf1 = F; F += NN*64;
    float* gpos = F; F += NN*3;
    float* T0   = F; F += ZZ*64;
    float* SC0  = F; F += ZZ*64;
    float* W3z  = F; F += 2*64*64;
    int* spec   = (int*)F; F += NN;
    int* elist  = (int*)F; F += EE;
    int* ecount = (int*)F; F += 1;

    const float* U0 = W_up;           const float* U1 = W_up   + 4*64*64;
    const float* O0 = W_out;          const float* O1 = W_out  + 4*64*64;
    const float* S0w= W_sc;           const float* S1w= W_sc   + 4*64*64;
    const float* P0 = W_prod;         const float* P1 = W_prod + 4*64*64;
    const float* M1_0=Wm1,  *M1_1=Wm1+8*64;
    const float* M2_0=Wm2,  *M2_1=Wm2+64*64;
    const float* asc1=a_sc+ZZ*64;
    const float* pl0=w_poly, *pl1=w_poly+3*64;
    float* W3z0 = W3z; float* W3z1 = W3z + 64*64;

    hipMemsetAsync(ecount, 0, sizeof(int), stream);
    hipMemsetAsync(agg0, 0, NN*64*sizeof(float), stream);
    hipMemsetAsync(agg1, 0, NN*64*sizeof(float), stream);
    hipMemsetAsync(ghb,  0, NN*64*sizeof(float), stream);
    hipMemsetAsync(gpos, 0, NN*3*sizeof(float), stream);
    hipMemsetAsync(out,  0, 8*sizeof(float), stream);

    k_geom<<<(EE+255)/256, 256, 0, stream>>>(pos, shifts, ei, u3, fr, dfr, elist, ecount);
    k_spec<<<(NN+255)/256, 256, 0, stream>>>(x, spec);
    k_pre <<<35, 256, 0, stream>>>(W_embed, U0, S0w, a_sc, Wm3, T0, SC0, W3z);

    // layer 0 forward
    k_edge_fwd<0><<<512,256,0,stream>>>(fr, elist, ecount, ei, spec, T0, nullptr,
                                        M1_0, M2_0, W3z0, agg0, t2b0, nullptr);
    k_node_fwd0<<<256,256,0,stream>>>(agg0, SC0, spec, O0, P0, U1, pl0, w_r0,
                                      s0, nf1, h1, nodee);
    // layer 1 forward
    k_edge_fwd<1><<<512,256,0,stream>>>(fr, elist, ecount, ei, spec, nullptr, h1,
                                        M1_1, M2_1, W3z1, agg1, t2b1, w0b1);
    k_node_fwd1<<<256,256,0,stream>>>(agg1, nf1, spec, O1, P1, S1w, asc1, pl1, s1, nf2);
    // readout
    k_read1<<<256,256,0,stream>>>(nf2, W_r1, w_r2, nodee, gnf2);

    // backward
    k_bnode<true><<<256,256,0,stream>>>(gnf2, s1, O1, P1, S1w, asc1, spec, pl1, gagg1, gacc);
    k_edge_bwd<1><<<512,256,0,stream>>>(fr, dfr, u3, elist, ecount, ei, spec, nullptr, h1,
                                        gagg1, t2b1, w0b1, M1_1, M2_1, W3z1, ghb, gpos);
    k_mmT<<<256,256,0,stream>>>(ghb, gacc, U1, w_r0, gnf1);
    k_bnode<false><<<256,256,0,stream>>>(gnf1, s0, O0, P0, nullptr, nullptr, spec, pl0,
                                         gagg0, nullptr);
    k_edge_bwd<0><<<512,256,0,stream>>>(fr, dfr, u3, elist, ecount, ei, spec, T0, nullptr,
                                        gagg0, t2b0, nullptr, M1_0, M2_0, W3z0, nullptr, gpos);

    k_final<<<(NN+255)/256,256,0,stream>>>(nodee, batch, gpos, out);
}

// Round 3
// 198.722 us; speedup vs baseline: 4.0016x; 1.8907x over previous
//
#include <hip/hip_runtime.h>
#include <math.h>

constexpr int NN = 4000;
constexpr int EE = 48000;
constexpr int ZZ = 10;
constexpr float RMAX = 5.0f;
constexpr float INV_AVG = 1.0f / 12.0f;

__device__ __forceinline__ float rl(float v, int lane){
    return __uint_as_float(__builtin_amdgcn_readlane(__float_as_uint(v), lane));
}
__device__ __forceinline__ float sigf(float x){ return 1.0f/(1.0f+__expf(-x)); }
__device__ __forceinline__ float siluf(float x){ return x*sigf(x); }
__device__ __forceinline__ float dsiluf(float x){ float s=sigf(x); return s*(1.0f+x*(1.0f-s)); }

__device__ __forceinline__ void pin64(float (&W)[64]){
#pragma unroll
    for (int i=0;i<64;i++) asm volatile("" : "+v"(W[i]));
}
__device__ __forceinline__ void pin8(float (&W)[8]){
#pragma unroll
    for (int i=0;i<8;i++) asm volatile("" : "+v"(W[i]));
}

// broadcast matvec: out_lane = sum_k readlane(src,k) * W[k]
__device__ __forceinline__ float bmv64(float src, const float (&W)[64]){
    float a0=0.f,a1=0.f,a2=0.f,a3=0.f;
#pragma unroll
    for (int k=0;k<64;k+=4){
        a0 += rl(src,k+0)*W[k+0];
        a1 += rl(src,k+1)*W[k+1];
        a2 += rl(src,k+2)*W[k+2];
        a3 += rl(src,k+3)*W[k+3];
    }
    return (a0+a1)+(a2+a3);
}
__device__ __forceinline__ void load_row64(const float* __restrict__ p, float (&W)[64]){
#pragma unroll
    for (int i=0;i<16;i++){
        float4 v = reinterpret_cast<const float4*>(p)[i];
        W[4*i]=v.x; W[4*i+1]=v.y; W[4*i+2]=v.z; W[4*i+3]=v.w;
    }
}
__device__ __forceinline__ void load_col64(const float* __restrict__ p, int lane, float (&W)[64]){
#pragma unroll
    for (int k=0;k<64;k++) W[k] = p[k*64+lane];
}

// ---------------- geometry + radial + compaction (edge blocks) ; species (node blocks) ----------------
__global__ void k_geom(const float* __restrict__ pos, const float* __restrict__ shifts,
                       const int* __restrict__ ei, const float* __restrict__ x,
                       int* __restrict__ spec,
                       float* __restrict__ u3c, float* __restrict__ frc, float* __restrict__ dfrc,
                       int* __restrict__ esrc, int* __restrict__ edst, int* __restrict__ ecount)
{
    int b = blockIdx.x;
    if (b >= 188){
        int n = (b-188)*256 + threadIdx.x;
        if (n < NN){
            int sp = 0;
#pragma unroll
            for (int j=0;j<ZZ;j++) if (x[n*ZZ+j] > 0.5f) sp = j;
            spec[n] = sp;
        }
        return;
    }
    int e = b*256 + threadIdx.x;
    if (e >= EE) return;
    int s = ei[e], r = ei[EE+e];
    float vx = pos[r*3+0]-pos[s*3+0]+shifts[e*3+0];
    float vy = pos[r*3+1]-pos[s*3+1]+shifts[e*3+1];
    float vz = pos[r*3+2]-pos[s*3+2]+shifts[e*3+2];
    float rr = sqrtf(vx*vx+vy*vy+vz*vz);
    float u = rr*(1.0f/RMAX);
    if (u >= 1.0f) return;              // env=0 -> zero message and zero force
    int slot = atomicAdd(ecount, 1);
    esrc[slot]=s; edst[slot]=r;
    float inv = 1.0f/rr;
    u3c[slot*3+0]=vx*inv; u3c[slot*3+1]=vy*inv; u3c[slot*3+2]=vz*inv;
    float u2=u*u, u4=u2*u2, u5=u4*u;
    float env  = 1.0f - 21.0f*u5 + 35.0f*u5*u - 15.0f*u5*u2;
    float om   = 1.0f-u;
    float denv = -21.0f*u4*om*om;
    const float A = 0.6324555320336759f;   // sqrt(2/RMAX)
    const float K1 = 3.14159265358979f/RMAX;
    float a  = K1*rr;
    float s1 = __sinf(a), c1 = __cosf(a);
    float sp = 0.0f, cp = 1.0f, sn = s1, cn = c1;
#pragma unroll
    for (int n=1;n<=8;n++){
        float k = (float)n*K1;
        float bess  = A*sn*inv;
        float dbess = A*(k*cn - sn*inv)*inv;
        frc [slot*8+n-1] = bess*env;
        dfrc[slot*8+n-1] = dbess*env + bess*denv;
        float s2 = 2.0f*c1*sn - sp; sp=sn; sn=s2;
        float c2 = 2.0f*c1*cn - cp; cp=cn; cn=c2;
    }
}

// per-species tables T0 = WE@U0, SC0 = (WE@S0)*asc0 ; gather Wm3 l=0 slice -> dense
__global__ void k_pre(const float* __restrict__ WE, const float* __restrict__ W_up,
                      const float* __restrict__ W_sc, const float* __restrict__ a_sc,
                      const float* __restrict__ Wm3,
                      float* __restrict__ T0, float* __restrict__ SC0, float* __restrict__ W3z)
{
    int b = blockIdx.x;
    if (b < 32){
        int idx = b*256 + threadIdx.x;       // 0..8191 : 2 layers x 4096
        int l = idx >> 12;
        int kc = idx & 4095;
        int k = kc >> 6, c = kc & 63;
        W3z[idx] = Wm3[l*64*256 + k*256 + 4*c];
    } else {
        int wv = (b-32)*4 + (threadIdx.x>>6);
        int lane = threadIdx.x & 63;
        if (wv < ZZ){
            float wev = WE[wv*64 + lane];
            float t=0.f, sc=0.f;
#pragma unroll
            for (int c=0;c<64;c++){
                float w = rl(wev,c);
                t  += w*W_up[c*64+lane];
                sc += w*W_sc[c*64+lane];
            }
            T0[wv*64+lane]  = t;
            SC0[wv*64+lane] = sc * a_sc[wv*64+lane];
        }
    }
}

// ---------------- fused edge MLP forward ----------------
template<int L>
__global__ __launch_bounds__(256,3)
void k_edge_fwd(const float* __restrict__ frc, const int* __restrict__ esrc,
                const int* __restrict__ edst, const int* __restrict__ ecount,
                const int* __restrict__ spec, const float* __restrict__ T0,
                const float* __restrict__ h1,
                const float* __restrict__ W1, const float* __restrict__ W2,
                const float* __restrict__ W3z,
                float* __restrict__ agg, float* __restrict__ t2b,
                float* __restrict__ w0b)
{
    int lane = threadIdx.x & 63;
    int wid  = (blockIdx.x*256 + threadIdx.x) >> 6;
    int nw   = gridDim.x*4;
    int cnt  = ecount[0];
    float W1c[8], W2c[64], W3c[64];
#pragma unroll
    for (int j=0;j<8;j++) W1c[j] = W1[j*64+lane];
    load_col64(W2,  lane, W2c);
    load_col64(W3z, lane, W3c);
    pin8(W1c); pin64(W2c); pin64(W3c);
    for (int slot=wid; slot<cnt; slot+=nw){
        int us = __builtin_amdgcn_readfirstlane(slot);
        int s = esrc[us], r = edst[us];
        float fv = frc[us*8 + (lane&7)];
        float t1=0.f;
#pragma unroll
        for (int j=0;j<8;j++) t1 += rl(fv,j)*W1c[j];
        float a1v = siluf(t1);
        float t2  = bmv64(a1v, W2c);
        t2b[(size_t)us*64+lane] = t2;
        float a2v = siluf(t2);
        float w0  = bmv64(a2v, W3c);
        if (L==1) w0b[(size_t)us*64+lane] = w0;
        float h = (L==0) ? T0[spec[s]*64+lane] : h1[s*64+lane];
        atomicAdd(&agg[r*64+lane], w0*h*INV_AVG);
    }
}

// ---------------- node update fwd, layer0 (+fused h1 and readout0) ----------------
__global__ __launch_bounds__(256,2)
void k_node_fwd0(const float* __restrict__ agg, const float* __restrict__ SC0,
                 const int* __restrict__ spec, const float* __restrict__ Wout,
                 const float* __restrict__ Wprod, const float* __restrict__ Wup1,
                 const float* __restrict__ poly, const float* __restrict__ wr0,
                 float* __restrict__ s0, float* __restrict__ nf1,
                 float* __restrict__ h1, float* __restrict__ nodee)
{
    int lane = threadIdx.x & 63;
    int n = (blockIdx.x*256 + threadIdx.x) >> 6;
    if (n >= NN) return;
    n = __builtin_amdgcn_readfirstlane(n);
    float Oc[64], Pc[64], Uc[64];
    load_col64(Wout, lane, Oc);
    load_col64(Wprod,lane, Pc);
    load_col64(Wup1, lane, Uc);
    pin64(Oc); pin64(Pc); pin64(Uc);
    float p0=poly[lane], p1=poly[64+lane], p2=poly[128+lane];
    float w0r = wr0[lane];
    float av = agg[n*64+lane];
    float s  = bmv64(av, Oc);
    float gate = p0 + p1*s + p2*s*s;
    float v  = s*gate;
    float nf = bmv64(v, Pc) + SC0[spec[n]*64+lane];
    s0 [n*64+lane] = s;
    nf1[n*64+lane] = nf;
    h1 [n*64+lane] = bmv64(nf, Uc);
    float ne = nf*w0r;
#pragma unroll
    for (int off=32;off;off>>=1) ne += __shfl_xor(ne,off);
    if (lane==0) nodee[n] = ne;
}

// ---------------- node update fwd, layer1 ----------------
__global__ __launch_bounds__(256,2)
void k_node_fwd1(const float* __restrict__ agg, const float* __restrict__ nf1,
                 const int* __restrict__ spec, const float* __restrict__ Wout,
                 const float* __restrict__ Wprod, const float* __restrict__ Wsc,
                 const float* __restrict__ asc, const float* __restrict__ poly,
                 float* __restrict__ s1, float* __restrict__ nf2)
{
    int lane = threadIdx.x & 63;
    int n = (blockIdx.x*256 + threadIdx.x) >> 6;
    if (n >= NN) return;
    n = __builtin_amdgcn_readfirstlane(n);
    float Oc[64], Pc[64], Sc[64];
    load_col64(Wout, lane, Oc);
    load_col64(Wprod,lane, Pc);
    load_col64(Wsc,  lane, Sc);
    pin64(Oc); pin64(Pc); pin64(Sc);
    float p0=poly[lane], p1=poly[64+lane], p2=poly[128+lane];
    float av  = agg[n*64+lane];
    float nfv = nf1[n*64+lane];
    float s   = bmv64(av, Oc);
    float gate = p0 + p1*s + p2*s*s;
    float v   = s*gate;
    float scp = bmv64(nfv, Sc);
    float nf  = bmv64(v, Pc) + scp*asc[spec[n]*64+lane];
    s1 [n*64+lane] = s;
    nf2[n*64+lane] = nf;
}

// ---------------- readout layer1: node_e final + gnf2 ----------------
__global__ __launch_bounds__(256,3)
void k_read1(const float* __restrict__ nf2, const float* __restrict__ Wr1,
             const float* __restrict__ wr2, float* __restrict__ nodee,
             float* __restrict__ gnf2)
{
    int lane = threadIdx.x & 63;
    int n = (blockIdx.x*256 + threadIdx.x) >> 6;
    if (n >= NN) return;
    n = __builtin_amdgcn_readfirstlane(n);
    int j = lane & 15;
    float Wcol[64];
#pragma unroll
    for (int c=0;c<64;c++) Wcol[c] = Wr1[c*16 + j];
    pin64(Wcol);
    float Wrow[16];
#pragma unroll
    for (int i=0;i<4;i++){
        float4 v = reinterpret_cast<const float4*>(Wr1 + lane*16)[i];
        Wrow[4*i]=v.x; Wrow[4*i+1]=v.y; Wrow[4*i+2]=v.z; Wrow[4*i+3]=v.w;
    }
    float w2 = wr2[j];
    float nv = nf2[n*64+lane];
    float z  = bmv64(nv, Wcol);        // z_{lane&15}, replicated 4x
    float ne = siluf(z)*w2;
#pragma unroll
    for (int off=32;off;off>>=1) ne += __shfl_xor(ne,off);
    ne *= 0.25f;
    float gz = w2*dsiluf(z);
    float g = 0.f;
#pragma unroll
    for (int jj=0;jj<16;jj++) g += rl(gz,jj)*Wrow[jj];
    gnf2[n*64+lane] = g;
    if (lane==0) nodee[n] += ne;
}

// ---------------- backward node layer1: gnf2 -> gagg1, gacc(sc path) ----------------
__global__ __launch_bounds__(256,2)
void k_bnode1(const float* __restrict__ gin, const float* __restrict__ sbuf,
              const float* __restrict__ Wout, const float* __restrict__ Wprod,
              const float* __restrict__ Wsc, const float* __restrict__ asc,
              const int* __restrict__ spec, const float* __restrict__ poly,
              float* __restrict__ gagg, float* __restrict__ gsc)
{
    int lane = threadIdx.x & 63;
    int n = (blockIdx.x*256 + threadIdx.x) >> 6;
    if (n >= NN) return;
    n = __builtin_amdgcn_readfirstlane(n);
    float Pr[64], Or[64], Sr[64];
    load_row64(Wprod + lane*64, Pr);
    load_row64(Wout  + lane*64, Or);
    load_row64(Wsc   + lane*64, Sr);
    pin64(Pr); pin64(Or); pin64(Sr);
    float p0=poly[lane], p1=poly[64+lane], p2=poly[128+lane];
    float g  = gin[n*64+lane];
    float gv = bmv64(g, Pr);
    float s  = sbuf[n*64+lane];
    float gate = p0 + p1*s + p2*s*s;
    float gs = gv*(gate + s*(p1 + 2.0f*p2*s));
    gagg[n*64+lane] = bmv64(gs, Or);
    float ga = g * asc[spec[n]*64+lane];
    gsc[n*64+lane] = bmv64(ga, Sr);
}

// ---------------- fused: gnf1 = ghb@U1^T + gacc + wr0 ; then bnode layer0 -> gagg0 ----------------
__global__ __launch_bounds__(256,2)
void k_bnode0(const float* __restrict__ ghb, const float* __restrict__ gacc,
              const float* __restrict__ Wup1, const float* __restrict__ wr0,
              const float* __restrict__ sbuf, const float* __restrict__ Wout,
              const float* __restrict__ Wprod, const float* __restrict__ poly,
              float* __restrict__ gagg)
{
    int lane = threadIdx.x & 63;
    int n = (blockIdx.x*256 + threadIdx.x) >> 6;
    if (n >= NN) return;
    n = __builtin_amdgcn_readfirstlane(n);
    float Ur[64], Pr[64], Or[64];
    load_row64(Wup1 + lane*64, Ur);
    load_row64(Wprod+ lane*64, Pr);
    load_row64(Wout + lane*64, Or);
    pin64(Ur); pin64(Pr); pin64(Or);
    float p0=poly[lane], p1=poly[64+lane], p2=poly[128+lane];
    float gh = ghb[n*64+lane];
    float g  = bmv64(gh, Ur) + gacc[n*64+lane] + wr0[lane];
    float gv = bmv64(g, Pr);
    float s  = sbuf[n*64+lane];
    float gate = p0 + p1*s + p2*s*s;
    float gs = gv*(gate + s*(p1 + 2.0f*p2*s));
    gagg[n*64+lane] = bmv64(gs, Or);
}

// ---------------- backward edge MLP -> gpos (+ghb for layer1) ----------------
template<int L>
__global__ __launch_bounds__(256,3)
void k_edge_bwd(const float* __restrict__ frc, const float* __restrict__ dfrc,
                const float* __restrict__ u3c, const int* __restrict__ esrc,
                const int* __restrict__ edst, const int* __restrict__ ecount,
                const int* __restrict__ spec, const float* __restrict__ T0,
                const float* __restrict__ h1, const float* __restrict__ gagg,
                const float* __restrict__ t2b, const float* __restrict__ w0b,
                const float* __restrict__ W1, const float* __restrict__ W2,
                const float* __restrict__ W3z,
                float* __restrict__ ghb, float* __restrict__ gpos)
{
    int lane = threadIdx.x & 63;
    int wid  = (blockIdx.x*256 + threadIdx.x) >> 6;
    int nw   = gridDim.x*4;
    int cnt  = ecount[0];
    float W3r[64], W2r[64], W1c[8];
    load_row64(W3z + lane*64, W3r);
    load_row64(W2  + lane*64, W2r);
#pragma unroll
    for (int j=0;j<8;j++) W1c[j] = W1[j*64+lane];
    pin64(W3r); pin64(W2r); pin8(W1c);
    for (int slot=wid; slot<cnt; slot+=nw){
        int us = __builtin_amdgcn_readfirstlane(slot);
        int s = esrc[us], r = edst[us];
        float gm = gagg[r*64+lane]*INV_AVG;
        float h  = (L==0) ? T0[spec[s]*64+lane] : h1[s*64+lane];
        float gw0 = gm*h;
        if (L==1) atomicAdd(&ghb[s*64+lane], gm*w0b[(size_t)us*64+lane]);
        float ga2 = bmv64(gw0, W3r);
        float t2v = t2b[(size_t)us*64+lane];
        float gt2 = ga2*dsiluf(t2v);
        float ga1 = bmv64(gt2, W2r);
        float fv  = frc [us*8+(lane&7)];
        float dfv = dfrc[us*8+(lane&7)];
        float t1=0.f, wd=0.f;
#pragma unroll
        for (int j=0;j<8;j++){ t1 += rl(fv,j)*W1c[j]; wd += rl(dfv,j)*W1c[j]; }
        float gt1 = ga1*dsiluf(t1);
        float p = gt1*wd;
#pragma unroll
        for (int off=32;off;off>>=1) p += __shfl_xor(p,off);
        if (lane<3) atomicAdd(&gpos[r*3+lane],  u3c[us*3+lane]*p);
        else if (lane>=32 && lane<35){ int d=lane-32; atomicAdd(&gpos[s*3+d], -u3c[us*3+d]*p); }
    }
}

// ---------------- final: snap reduce, node_e copy, forces ----------------
__global__ void k_final(const float* __restrict__ node_e, const int* __restrict__ batch,
                        const float* __restrict__ gpos, float* __restrict__ out)
{
    __shared__ float part[8];
    int tid=threadIdx.x;
    if (tid<8) part[tid]=0.0f;
    __syncthreads();
    int n = blockIdx.x*256 + tid;
    if (n<NN){
        float ne = node_e[n];
        out[8+n] = ne;
        atomicAdd(&part[batch[n]], ne);
        out[8+NN + n*3+0] = -gpos[n*3+0];
        out[8+NN + n*3+1] = -gpos[n*3+1];
        out[8+NN + n*3+2] = -gpos[n*3+2];
    }
    __syncthreads();
    if (tid<8) atomicAdd(&out[tid], part[tid]);
}

extern "C" void kernel_launch(void* const* d_in, const int* in_sizes, int n_in,
                              void* d_out, int out_size, void* d_ws, size_t ws_size,
                              hipStream_t stream)
{
    (void)in_sizes; (void)n_in; (void)out_size; (void)ws_size;
    const float* pos    = (const float*)d_in[0];
    const float* x      = (const float*)d_in[1];
    const float* shifts = (const float*)d_in[2];
    const float* W_embed= (const float*)d_in[3];
    const float* W_up   = (const float*)d_in[4];
    const float* Wm1    = (const float*)d_in[5];
    const float* Wm2    = (const float*)d_in[6];
    const float* Wm3    = (const float*)d_in[7];
    const float* W_out  = (const float*)d_in[8];
    const float* W_sc   = (const float*)d_in[9];
    const float* a_sc   = (const float*)d_in[10];
    const float* w_poly = (const float*)d_in[11];
    const float* W_prod = (const float*)d_in[12];
    const float* w_r0   = (const float*)d_in[13];
    const float* W_r1   = (const float*)d_in[14];
    const float* w_r2   = (const float*)d_in[15];
    const int*   ei     = (const int*)d_in[16];
    const int*   batch  = (const int*)d_in[17];
    float* out = (float*)d_out;

    float* F = (float*)d_ws;
    // ---- zero region (one memset) ----
    float* agg0 = F; F += NN*64;
    float* agg1 = F; F += NN*64;
    float* ghb  = F; F += NN*64;
    float* gpos = F; F += NN*3;
    int* ecount = (int*)F; F += 1;
    size_t zero_bytes = (size_t)(3*NN*64 + 3*NN)*4 + 4;
    // ---- rest ----
    float* u3c  = F; F += 3*EE;
    float* frc  = F; F += 8*EE;
    float* dfrc = F; F += 8*EE;
    float* t2b0 = F; F += (size_t)EE*64;
    float* t2b1 = F; F += (size_t)EE*64;
    float* w0b1 = F; F += (size_t)EE*64;
    float* h1   = F; F += NN*64;
    float* nf1  = F; F += NN*64;
    float* nf2  = F; F += NN*64;
    float* s0   = F; F += NN*64;
    float* s1   = F; F += NN*64;
    float* nodee= F; F += NN;
    float* gnf2 = F; F += NN*64;
    float* gagg1= F; F += NN*64;
    float* gagg0= F; F += NN*64;
    float* gacc = F; F += NN*64;
    float* T0   = F; F += ZZ*64;
    float* SC0  = F; F += ZZ*64;
    float* W3z  = F; F += 2*64*64;
    int* spec   = (int*)F; F += NN;
    int* esrc   = (int*)F; F += EE;
    int* edst   = (int*)F; F += EE;

    const float* U0 = W_up;           const float* U1 = W_up   + 4*64*64;
    const float* O0 = W_out;          const float* O1 = W_out  + 4*64*64;
    const float* S0w= W_sc;           const float* S1w= W_sc   + 4*64*64;
    const float* P0 = W_prod;         const float* P1 = W_prod + 4*64*64;
    const float* M1_0=Wm1,  *M1_1=Wm1+8*64;
    const float* M2_0=Wm2,  *M2_1=Wm2+64*64;
    const float* asc1=a_sc+ZZ*64;
    const float* pl0=w_poly, *pl1=w_poly+3*64;
    float* W3z0 = W3z; float* W3z1 = W3z + 64*64;

    hipMemsetAsync(agg0, 0, zero_bytes, stream);
    hipMemsetAsync(out,  0, 8*sizeof(float), stream);

    k_geom<<<204, 256, 0, stream>>>(pos, shifts, ei, x, spec, u3c, frc, dfrc, esrc, edst, ecount);
    k_pre <<<35, 256, 0, stream>>>(W_embed, U0, S0w, a_sc, Wm3, T0, SC0, W3z);

    // layer 0 forward
    k_edge_fwd<0><<<1024,256,0,stream>>>(frc, esrc, edst, ecount, spec, T0, nullptr,
                                         M1_0, M2_0, W3z0, agg0, t2b0, nullptr);
    k_node_fwd0<<<1000,256,0,stream>>>(agg0, SC0, spec, O0, P0, U1, pl0, w_r0,
                                       s0, nf1, h1, nodee);
    // layer 1 forward
    k_edge_fwd<1><<<1024,256,0,stream>>>(frc, esrc, edst, ecount, spec, nullptr, h1,
                                         M1_1, M2_1, W3z1, agg1, t2b1, w0b1);
    k_node_fwd1<<<1000,256,0,stream>>>(agg1, nf1, spec, O1, P1, S1w, asc1, pl1, s1, nf2);
    k_read1<<<1000,256,0,stream>>>(nf2, W_r1, w_r2, nodee, gnf2);

    // backward
    k_bnode1<<<1000,256,0,stream>>>(gnf2, s1, O1, P1, S1w, asc1, spec, pl1, gagg1, gacc);
    k_edge_bwd<1><<<1024,256,0,stream>>>(frc, dfrc, u3c, esrc, edst, ecount, spec, nullptr, h1,
                                         gagg1, t2b1, w0b1, M1_1, M2_1, W3z1, ghb, gpos);
    k_bnode0<<<1000,256,0,stream>>>(ghb, gacc, U1, w_r0, s0, O0, P0, pl0, gagg0);
    k_edge_bwd<0><<<1024,256,0,stream>>>(frc, dfrc, u3c, esrc, edst, ecount, spec, T0, nullptr,
                                         gagg0, t2b0, nullptr, M1_0, M2_0, W3z0, nullptr, gpos);

    k_final<<<16,256,0,stream>>>(nodee, batch, gpos, out);
}

// Round 4
// 150.875 us; speedup vs baseline: 5.2706x; 1.3171x over previous
//
#include <hip/hip_runtime.h>
#include <math.h>

constexpr int NN = 4000;
constexpr int EE = 48000;
constexpr int ZZ = 10;
constexpr float RMAX = 5.0f;
constexpr float INV_AVG = 1.0f / 12.0f;

// zero region: agg0, agg1, ghb (NN*64 each) + gpos (NN*3) + ecount/pad (4)
constexpr int ZERO_F4 = (3*NN*64 + 3*NN + 4) / 4;   // float4 count (780004/4)

__device__ __forceinline__ float rl(float v, int lane){
    return __uint_as_float(__builtin_amdgcn_readlane(__float_as_uint(v), lane));
}
__device__ __forceinline__ float sigf(float x){ return 1.0f/(1.0f+__expf(-x)); }
__device__ __forceinline__ float siluf(float x){ return x*sigf(x); }
__device__ __forceinline__ float dsiluf(float x){ float s=sigf(x); return s*(1.0f+x*(1.0f-s)); }

__device__ __forceinline__ void pin64(float (&W)[64]){
#pragma unroll
    for (int i=0;i<64;i++) asm volatile("" : "+v"(W[i]));
}
__device__ __forceinline__ void pin8(float (&W)[8]){
#pragma unroll
    for (int i=0;i<8;i++) asm volatile("" : "+v"(W[i]));
}

__device__ __forceinline__ float bmv64(float src, const float (&W)[64]){
    float a0=0.f,a1=0.f,a2=0.f,a3=0.f;
#pragma unroll
    for (int k=0;k<64;k+=4){
        a0 += rl(src,k+0)*W[k+0];
        a1 += rl(src,k+1)*W[k+1];
        a2 += rl(src,k+2)*W[k+2];
        a3 += rl(src,k+3)*W[k+3];
    }
    return (a0+a1)+(a2+a3);
}
__device__ __forceinline__ void load_row64(const float* __restrict__ p, float (&W)[64]){
#pragma unroll
    for (int i=0;i<16;i++){
        float4 v = reinterpret_cast<const float4*>(p)[i];
        W[4*i]=v.x; W[4*i+1]=v.y; W[4*i+2]=v.z; W[4*i+3]=v.w;
    }
}
__device__ __forceinline__ void load_col64(const float* __restrict__ p, int lane, float (&W)[64]){
#pragma unroll
    for (int k=0;k<64;k++) W[k] = p[k*64+lane];
}

// ---------------- fast zero of workspace accumulators + out[0..7] ----------------
__global__ void k_zero(float4* __restrict__ z, float* __restrict__ out)
{
    int i = blockIdx.x*256 + threadIdx.x;
    if (i < ZERO_F4) z[i] = make_float4(0.f,0.f,0.f,0.f);
    if (blockIdx.x==0 && threadIdx.x<8) out[threadIdx.x] = 0.0f;
}

// ---------------- geometry+compaction / species / weight-precompute (block roles) ----------------
__global__ void k_geom(const float* __restrict__ pos, const float* __restrict__ shifts,
                       const int* __restrict__ ei, const float* __restrict__ x,
                       const float* __restrict__ WE, const float* __restrict__ W_up,
                       const float* __restrict__ W_sc, const float* __restrict__ a_sc,
                       const float* __restrict__ Wm3,
                       int* __restrict__ spec,
                       float* __restrict__ u3c, float* __restrict__ frc, float* __restrict__ dfrc,
                       int* __restrict__ esrc, int* __restrict__ edst, int* __restrict__ ecount,
                       float* __restrict__ T0, float* __restrict__ SC0, float* __restrict__ W3z)
{
    int b = blockIdx.x;
    if (b >= 236){                       // T0/SC0: per-species tables (3 blocks, 12 waves)
        int wv = (b-236)*4 + (threadIdx.x>>6);
        int lane = threadIdx.x & 63;
        if (wv < ZZ){
            float wev = WE[wv*64 + lane];
            float t=0.f, sc=0.f;
#pragma unroll
            for (int c=0;c<64;c++){
                float w = rl(wev,c);
                t  += w*W_up[c*64+lane];
                sc += w*W_sc[c*64+lane];
            }
            T0[wv*64+lane]  = t;
            SC0[wv*64+lane] = sc * a_sc[wv*64+lane];
        }
        return;
    }
    if (b >= 204){                       // W3z gather: Wm3 l=0 slice -> dense 2x64x64
        int idx = (b-204)*256 + threadIdx.x;
        int l = idx >> 12;
        int kc = idx & 4095;
        int k = kc >> 6, c = kc & 63;
        W3z[idx] = Wm3[l*64*256 + k*256 + 4*c];
        return;
    }
    if (b >= 188){                       // species from one-hot
        int n = (b-188)*256 + threadIdx.x;
        if (n < NN){
            int sp = 0;
#pragma unroll
            for (int j=0;j<ZZ;j++) if (x[n*ZZ+j] > 0.5f) sp = j;
            spec[n] = sp;
        }
        return;
    }
    int e = b*256 + threadIdx.x;         // edges: geometry + radial + compaction
    if (e >= EE) return;
    int s = ei[e], r = ei[EE+e];
    float vx = pos[r*3+0]-pos[s*3+0]+shifts[e*3+0];
    float vy = pos[r*3+1]-pos[s*3+1]+shifts[e*3+1];
    float vz = pos[r*3+2]-pos[s*3+2]+shifts[e*3+2];
    float rr = sqrtf(vx*vx+vy*vy+vz*vz);
    float u = rr*(1.0f/RMAX);
    if (u >= 1.0f) return;               // env=0 -> zero message and zero force
    int slot = atomicAdd(ecount, 1);
    esrc[slot]=s; edst[slot]=r;
    float inv = 1.0f/rr;
    u3c[slot*3+0]=vx*inv; u3c[slot*3+1]=vy*inv; u3c[slot*3+2]=vz*inv;
    float u2=u*u, u4=u2*u2, u5=u4*u;
    float env  = 1.0f - 21.0f*u5 + 35.0f*u5*u - 15.0f*u5*u2;
    float om   = 1.0f-u;
    float denv = -21.0f*u4*om*om;
    const float A = 0.6324555320336759f;    // sqrt(2/RMAX)
    const float K1 = 3.14159265358979f/RMAX;
    float a  = K1*rr;
    float s1 = __sinf(a), c1 = __cosf(a);
    float sp = 0.0f, cp = 1.0f, sn = s1, cn = c1;
#pragma unroll
    for (int n=1;n<=8;n++){
        float k = (float)n*K1;
        float bess  = A*sn*inv;
        float dbess = A*(k*cn - sn*inv)*inv;
        frc [slot*8+n-1] = bess*env;
        dfrc[slot*8+n-1] = dbess*env + bess*denv;
        float s2 = 2.0f*c1*sn - sp; sp=sn; sn=s2;
        float c2 = 2.0f*c1*cn - cp; cp=cn; cn=c2;
    }
}

// ---------------- fused edge MLP forward ----------------
template<int L>
__global__ __launch_bounds__(256,3)
void k_edge_fwd(const float* __restrict__ frc, const int* __restrict__ esrc,
                const int* __restrict__ edst, const int* __restrict__ ecount,
                const int* __restrict__ spec, const float* __restrict__ T0,
                const float* __restrict__ h1,
                const float* __restrict__ W1, const float* __restrict__ W2,
                const float* __restrict__ W3z,
                float* __restrict__ agg, float* __restrict__ t2b,
                float* __restrict__ w0b)
{
    int lane = threadIdx.x & 63;
    int wid  = (blockIdx.x*256 + threadIdx.x) >> 6;
    int nw   = gridDim.x*4;
    int cnt  = ecount[0];
    float W1c[8], W2c[64], W3c[64];
#pragma unroll
    for (int j=0;j<8;j++) W1c[j] = W1[j*64+lane];
    load_col64(W2,  lane, W2c);
    load_col64(W3z, lane, W3c);
    pin8(W1c); pin64(W2c); pin64(W3c);
    for (int slot=wid; slot<cnt; slot+=nw){
        int us = __builtin_amdgcn_readfirstlane(slot);
        int s = esrc[us], r = edst[us];
        float fv = frc[us*8 + (lane&7)];
        float t1=0.f;
#pragma unroll
        for (int j=0;j<8;j++) t1 += rl(fv,j)*W1c[j];
        float a1v = siluf(t1);
        float t2  = bmv64(a1v, W2c);
        t2b[(size_t)us*64+lane] = t2;
        float a2v = siluf(t2);
        float w0  = bmv64(a2v, W3c);
        if (L==1) w0b[(size_t)us*64+lane] = w0;
        float h = (L==0) ? T0[spec[s]*64+lane] : h1[s*64+lane];
        atomicAdd(&agg[r*64+lane], w0*h*INV_AVG);
    }
}

// ---------------- node update fwd, layer0 (+fused h1 and readout0) ----------------
__global__ __launch_bounds__(256,2)
void k_node_fwd0(const float* __restrict__ agg, const float* __restrict__ SC0,
                 const int* __restrict__ spec, const float* __restrict__ Wout,
                 const float* __restrict__ Wprod, const float* __restrict__ Wup1,
                 const float* __restrict__ poly, const float* __restrict__ wr0,
                 float* __restrict__ s0, float* __restrict__ nf1,
                 float* __restrict__ h1, float* __restrict__ nodee)
{
    int lane = threadIdx.x & 63;
    int wid = (blockIdx.x*256 + threadIdx.x) >> 6;
    int nw  = gridDim.x*4;
    float Oc[64], Pc[64], Uc[64];
    load_col64(Wout, lane, Oc);
    load_col64(Wprod,lane, Pc);
    load_col64(Wup1, lane, Uc);
    pin64(Oc); pin64(Pc); pin64(Uc);
    float p0=poly[lane], p1=poly[64+lane], p2=poly[128+lane];
    float w0r = wr0[lane];
    for (int nn=wid; nn<NN; nn+=nw){
        int n = __builtin_amdgcn_readfirstlane(nn);
        float av = agg[n*64+lane];
        float s  = bmv64(av, Oc);
        float gate = p0 + p1*s + p2*s*s;
        float v  = s*gate;
        float nf = bmv64(v, Pc) + SC0[spec[n]*64+lane];
        s0 [n*64+lane] = s;
        nf1[n*64+lane] = nf;
        h1 [n*64+lane] = bmv64(nf, Uc);
        float ne = nf*w0r;
#pragma unroll
        for (int off=32;off;off>>=1) ne += __shfl_xor(ne,off);
        if (lane==0) nodee[n] = ne;
    }
}

// ---------------- node update fwd, layer1 ----------------
__global__ __launch_bounds__(256,2)
void k_node_fwd1(const float* __restrict__ agg, const float* __restrict__ nf1,
                 const int* __restrict__ spec, const float* __restrict__ Wout,
                 const float* __restrict__ Wprod, const float* __restrict__ Wsc,
                 const float* __restrict__ asc, const float* __restrict__ poly,
                 float* __restrict__ s1, float* __restrict__ nf2)
{
    int lane = threadIdx.x & 63;
    int wid = (blockIdx.x*256 + threadIdx.x) >> 6;
    int nw  = gridDim.x*4;
    float Oc[64], Pc[64], Sc[64];
    load_col64(Wout, lane, Oc);
    load_col64(Wprod,lane, Pc);
    load_col64(Wsc,  lane, Sc);
    pin64(Oc); pin64(Pc); pin64(Sc);
    float p0=poly[lane], p1=poly[64+lane], p2=poly[128+lane];
    for (int nn=wid; nn<NN; nn+=nw){
        int n = __builtin_amdgcn_readfirstlane(nn);
        float av  = agg[n*64+lane];
        float nfv = nf1[n*64+lane];
        float s   = bmv64(av, Oc);
        float gate = p0 + p1*s + p2*s*s;
        float v   = s*gate;
        float scp = bmv64(nfv, Sc);
        float nf  = bmv64(v, Pc) + scp*asc[spec[n]*64+lane];
        s1 [n*64+lane] = s;
        nf2[n*64+lane] = nf;
    }
}

// ---------------- readout layer1: node_e final + gnf2 ----------------
__global__ __launch_bounds__(256,3)
void k_read1(const float* __restrict__ nf2, const float* __restrict__ Wr1,
             const float* __restrict__ wr2, float* __restrict__ nodee,
             float* __restrict__ gnf2)
{
    int lane = threadIdx.x & 63;
    int wid = (blockIdx.x*256 + threadIdx.x) >> 6;
    int nw  = gridDim.x*4;
    int j = lane & 15;
    float Wcol[64];
#pragma unroll
    for (int c=0;c<64;c++) Wcol[c] = Wr1[c*16 + j];
    pin64(Wcol);
    float Wrow[16];
#pragma unroll
    for (int i=0;i<4;i++){
        float4 v = reinterpret_cast<const float4*>(Wr1 + lane*16)[i];
        Wrow[4*i]=v.x; Wrow[4*i+1]=v.y; Wrow[4*i+2]=v.z; Wrow[4*i+3]=v.w;
    }
    float w2 = wr2[j];
    for (int nn=wid; nn<NN; nn+=nw){
        int n = __builtin_amdgcn_readfirstlane(nn);
        float nv = nf2[n*64+lane];
        float z  = bmv64(nv, Wcol);        // z_{lane&15}, replicated 4x
        float ne = siluf(z)*w2;
#pragma unroll
        for (int off=32;off;off>>=1) ne += __shfl_xor(ne,off);
        ne *= 0.25f;
        float gz = w2*dsiluf(z);
        float g = 0.f;
#pragma unroll
        for (int jj=0;jj<16;jj++) g += rl(gz,jj)*Wrow[jj];
        gnf2[n*64+lane] = g;
        if (lane==0) nodee[n] += ne;
    }
}

// ---------------- backward node layer1: gnf2 -> gagg1, gacc(sc path) ----------------
__global__ __launch_bounds__(256,2)
void k_bnode1(const float* __restrict__ gin, const float* __restrict__ sbuf,
              const float* __restrict__ Wout, const float* __restrict__ Wprod,
              const float* __restrict__ Wsc, const float* __restrict__ asc,
              const int* __restrict__ spec, const float* __restrict__ poly,
              float* __restrict__ gagg, float* __restrict__ gsc)
{
    int lane = threadIdx.x & 63;
    int wid = (blockIdx.x*256 + threadIdx.x) >> 6;
    int nw  = gridDim.x*4;
    float Pr[64], Or[64], Sr[64];
    load_row64(Wprod + lane*64, Pr);
    load_row64(Wout  + lane*64, Or);
    load_row64(Wsc   + lane*64, Sr);
    pin64(Pr); pin64(Or); pin64(Sr);
    float p0=poly[lane], p1=poly[64+lane], p2=poly[128+lane];
    for (int nn=wid; nn<NN; nn+=nw){
        int n = __builtin_amdgcn_readfirstlane(nn);
        float g  = gin[n*64+lane];
        float gv = bmv64(g, Pr);
        float s  = sbuf[n*64+lane];
        float gate = p0 + p1*s + p2*s*s;
        float gs = gv*(gate + s*(p1 + 2.0f*p2*s));
        gagg[n*64+lane] = bmv64(gs, Or);
        float ga = g * asc[spec[n]*64+lane];
        gsc[n*64+lane] = bmv64(ga, Sr);
    }
}

// ---------------- fused: gnf1 = ghb@U1^T + gacc + wr0 ; then bnode layer0 -> gagg0 ----------------
__global__ __launch_bounds__(256,2)
void k_bnode0(const float* __restrict__ ghb, const float* __restrict__ gacc,
              const float* __restrict__ Wup1, const float* __restrict__ wr0,
              const float* __restrict__ sbuf, const float* __restrict__ Wout,
              const float* __restrict__ Wprod, const float* __restrict__ poly,
              float* __restrict__ gagg)
{
    int lane = threadIdx.x & 63;
    int wid = (blockIdx.x*256 + threadIdx.x) >> 6;
    int nw  = gridDim.x*4;
    float Ur[64], Pr[64], Or[64];
    load_row64(Wup1 + lane*64, Ur);
    load_row64(Wprod+ lane*64, Pr);
    load_row64(Wout + lane*64, Or);
    pin64(Ur); pin64(Pr); pin64(Or);
    float p0=poly[lane], p1=poly[64+lane], p2=poly[128+lane];
    for (int nn=wid; nn<NN; nn+=nw){
        int n = __builtin_amdgcn_readfirstlane(nn);
        float gh = ghb[n*64+lane];
        float g  = bmv64(gh, Ur) + gacc[n*64+lane] + wr0[lane];
        float gv = bmv64(g, Pr);
        float s  = sbuf[n*64+lane];
        float gate = p0 + p1*s + p2*s*s;
        float gs = gv*(gate + s*(p1 + 2.0f*p2*s));
        gagg[n*64+lane] = bmv64(gs, Or);
    }
}

// ---------------- backward edge MLP -> gpos (+ghb for layer1) ----------------
template<int L>
__global__ __launch_bounds__(256,3)
void k_edge_bwd(const float* __restrict__ frc, const float* __restrict__ dfrc,
                const float* __restrict__ u3c, const int* __restrict__ esrc,
                const int* __restrict__ edst, const int* __restrict__ ecount,
                const int* __restrict__ spec, const float* __restrict__ T0,
                const float* __restrict__ h1, const float* __restrict__ gagg,
                const float* __restrict__ t2b, const float* __restrict__ w0b,
                const float* __restrict__ W1, const float* __restrict__ W2,
                const float* __restrict__ W3z,
                float* __restrict__ ghb, float* __restrict__ gpos)
{
    int lane = threadIdx.x & 63;
    int wid  = (blockIdx.x*256 + threadIdx.x) >> 6;
    int nw   = gridDim.x*4;
    int cnt  = ecount[0];
    float W3r[64], W2r[64], W1c[8];
    load_row64(W3z + lane*64, W3r);
    load_row64(W2  + lane*64, W2r);
#pragma unroll
    for (int j=0;j<8;j++) W1c[j] = W1[j*64+lane];
    pin64(W3r); pin64(W2r); pin8(W1c);
    for (int slot=wid; slot<cnt; slot+=nw){
        int us = __builtin_amdgcn_readfirstlane(slot);
        int s = esrc[us], r = edst[us];
        float gm = gagg[r*64+lane]*INV_AVG;
        float h  = (L==0) ? T0[spec[s]*64+lane] : h1[s*64+lane];
        float gw0 = gm*h;
        if (L==1) atomicAdd(&ghb[s*64+lane], gm*w0b[(size_t)us*64+lane]);
        float ga2 = bmv64(gw0, W3r);
        float t2v = t2b[(size_t)us*64+lane];
        float gt2 = ga2*dsiluf(t2v);
        float ga1 = bmv64(gt2, W2r);
        float fv  = frc [us*8+(lane&7)];
        float dfv = dfrc[us*8+(lane&7)];
        float t1=0.f, wd=0.f;
#pragma unroll
        for (int j=0;j<8;j++){ t1 += rl(fv,j)*W1c[j]; wd += rl(dfv,j)*W1c[j]; }
        float gt1 = ga1*dsiluf(t1);
        float p = gt1*wd;
#pragma unroll
        for (int off=32;off;off>>=1) p += __shfl_xor(p,off);
        if (lane<3) atomicAdd(&gpos[r*3+lane],  u3c[us*3+lane]*p);
        else if (lane>=32 && lane<35){ int d=lane-32; atomicAdd(&gpos[s*3+d], -u3c[us*3+d]*p); }
    }
}

// ---------------- final: snap reduce, node_e copy, forces ----------------
__global__ void k_final(const float* __restrict__ node_e, const int* __restrict__ batch,
                        const float* __restrict__ gpos, float* __restrict__ out)
{
    __shared__ float part[8];
    int tid=threadIdx.x;
    if (tid<8) part[tid]=0.0f;
    __syncthreads();
    int n = blockIdx.x*256 + tid;
    if (n<NN){
        float ne = node_e[n];
        out[8+n] = ne;
        atomicAdd(&part[batch[n]], ne);
        out[8+NN + n*3+0] = -gpos[n*3+0];
        out[8+NN + n*3+1] = -gpos[n*3+1];
        out[8+NN + n*3+2] = -gpos[n*3+2];
    }
    __syncthreads();
    if (tid<8) atomicAdd(&out[tid], part[tid]);
}

extern "C" void kernel_launch(void* const* d_in, const int* in_sizes, int n_in,
                              void* d_out, int out_size, void* d_ws, size_t ws_size,
                              hipStream_t stream)
{
    (void)in_sizes; (void)n_in; (void)out_size; (void)ws_size;
    const float* pos    = (const float*)d_in[0];
    const float* x      = (const float*)d_in[1];
    const float* shifts = (const float*)d_in[2];
    const float* W_embed= (const float*)d_in[3];
    const float* W_up   = (const float*)d_in[4];
    const float* Wm1    = (const float*)d_in[5];
    const float* Wm2    = (const float*)d_in[6];
    const float* Wm3    = (const float*)d_in[7];
    const float* W_out  = (const float*)d_in[8];
    const float* W_sc   = (const float*)d_in[9];
    const float* a_sc   = (const float*)d_in[10];
    const float* w_poly = (const float*)d_in[11];
    const float* W_prod = (const float*)d_in[12];
    const float* w_r0   = (const float*)d_in[13];
    const float* W_r1   = (const float*)d_in[14];
    const float* w_r2   = (const float*)d_in[15];
    const int*   ei     = (const int*)d_in[16];
    const int*   batch  = (const int*)d_in[17];
    float* out = (float*)d_out;

    float* F = (float*)d_ws;
    // ---- zero region (k_zero covers exactly these, float4-aligned) ----
    float* agg0 = F; F += NN*64;
    float* agg1 = F; F += NN*64;
    float* ghb  = F; F += NN*64;
    float* gpos = F; F += NN*3;
    int* ecount = (int*)F; F += 4;       // +pad to float4 multiple
    // ---- rest ----
    float* u3c  = F; F += 3*EE;
    float* frc  = F; F += 8*EE;
    float* dfrc = F; F += 8*EE;
    float* t2b0 = F; F += (size_t)EE*64;
    float* t2b1 = F; F += (size_t)EE*64;
    float* w0b1 = F; F += (size_t)EE*64;
    float* h1   = F; F += NN*64;
    float* nf1  = F; F += NN*64;
    float* nf2  = F; F += NN*64;
    float* s0   = F; F += NN*64;
    float* s1   = F; F += NN*64;
    float* nodee= F; F += NN;
    float* gnf2 = F; F += NN*64;
    float* gagg1= F; F += NN*64;
    float* gagg0= F; F += NN*64;
    float* gacc = F; F += NN*64;
    float* T0   = F; F += ZZ*64;
    float* SC0  = F; F += ZZ*64;
    float* W3z  = F; F += 2*64*64;
    int* spec   = (int*)F; F += NN;
    int* esrc   = (int*)F; F += EE;
    int* edst   = (int*)F; F += EE;

    const float* U0 = W_up;           const float* U1 = W_up   + 4*64*64;
    const float* O0 = W_out;          const float* O1 = W_out  + 4*64*64;
    const float* S0w= W_sc;           const float* S1w= W_sc   + 4*64*64;
    const float* P0 = W_prod;         const float* P1 = W_prod + 4*64*64;
    const float* M1_0=Wm1,  *M1_1=Wm1+8*64;
    const float* M2_0=Wm2,  *M2_1=Wm2+64*64;
    const float* asc1=a_sc+ZZ*64;
    const float* pl0=w_poly, *pl1=w_poly+3*64;
    float* W3z0 = W3z; float* W3z1 = W3z + 64*64;

    k_zero<<<(ZERO_F4+255)/256, 256, 0, stream>>>((float4*)d_ws, out);
    k_geom<<<239, 256, 0, stream>>>(pos, shifts, ei, x, W_embed, U0, S0w, a_sc, Wm3,
                                    spec, u3c, frc, dfrc, esrc, edst, ecount, T0, SC0, W3z);

    // layer 0 forward
    k_edge_fwd<0><<<768,256,0,stream>>>(frc, esrc, edst, ecount, spec, T0, nullptr,
                                        M1_0, M2_0, W3z0, agg0, t2b0, nullptr);
    k_node_fwd0<<<500,256,0,stream>>>(agg0, SC0, spec, O0, P0, U1, pl0, w_r0,
                                      s0, nf1, h1, nodee);
    // layer 1 forward
    k_edge_fwd<1><<<768,256,0,stream>>>(frc, esrc, edst, ecount, spec, nullptr, h1,
                                        M1_1, M2_1, W3z1, agg1, t2b1, w0b1);
    k_node_fwd1<<<500,256,0,stream>>>(agg1, nf1, spec, O1, P1, S1w, asc1, pl1, s1, nf2);
    k_read1<<<500,256,0,stream>>>(nf2, W_r1, w_r2, nodee, gnf2);

    // backward
    k_bnode1<<<500,256,0,stream>>>(gnf2, s1, O1, P1, S1w, asc1, spec, pl1, gagg1, gacc);
    k_edge_bwd<1><<<768,256,0,stream>>>(frc, dfrc, u3c, esrc, edst, ecount, spec, nullptr, h1,
                                        gagg1, t2b1, w0b1, M1_1, M2_1, W3z1, ghb, gpos);
    k_bnode0<<<500,256,0,stream>>>(ghb, gacc, U1, w_r0, s0, O0, P0, pl0, gagg0);
    k_edge_bwd<0><<<768,256,0,stream>>>(frc, dfrc, u3c, esrc, edst, ecount, spec, T0, nullptr,
                                        gagg0, t2b0, nullptr, M1_0, M2_0, W3z0, nullptr, gpos);

    k_final<<<16,256,0,stream>>>(nodee, batch, gpos, out);
}